// Round 5
// baseline (499.457 us; speedup 1.0000x reference)
//
#include <hip/hip_runtime.h>
#include <hip/hip_bf16.h>

typedef __hip_bfloat16 bf16;
typedef __attribute__((ext_vector_type(8))) short bf16x8;   // 8 bf16 = 4 VGPRs (MFMA A/B frag)
typedef __attribute__((ext_vector_type(4))) float f32x4;    // MFMA C/D frag
typedef unsigned int u32;
typedef unsigned short u16;

#define MFMA(a,b,c) __builtin_amdgcn_mfma_f32_16x16x32_bf16((a),(b),(c),0,0,0)

__device__ __forceinline__ u16 f32_to_bf16_rtne(float f) {
  u32 b = __builtin_bit_cast(u32, f);
  b += 0x7FFFu + ((b >> 16) & 1u);
  return (u16)(b >> 16);
}
__device__ __forceinline__ float bf16_to_f32(u16 h) {
  return __builtin_bit_cast(float, (u32)h << 16);
}
// pack two f32 -> (lo: a, hi: b) bf16 pair, RTNE; v_perm does the byte-select
__device__ __forceinline__ u32 pk2bf(float a, float b) {
  u32 ua = __builtin_bit_cast(u32, a); ua += 0x7FFFu + ((ua >> 16) & 1u);
  u32 ub = __builtin_bit_cast(u32, b); ub += 0x7FFFu + ((ub >> 16) & 1u);
  return __builtin_amdgcn_perm(ub, ua, 0x07060302u);
}

// lgkm-only barrier: LDS ops drained, but outstanding global->reg prefetch
// loads stay IN FLIGHT across the barrier (no vmcnt(0) drain).
__device__ __forceinline__ void barrier_lgkm() {
  asm volatile("s_waitcnt lgkmcnt(0)\n\ts_barrier" ::: "memory");
}

static constexpr float SL2E = 0.125f * 1.44269504f;  // 1/sqrt(dh) * log2(e)

// ---------------------------------------------------------------------------
// Detect input dtype. mode=1: f32 inputs. mode=0: bf16 inputs.
// ---------------------------------------------------------------------------
__global__ void detect_mode(const u16* __restrict__ x_raw, int* __restrict__ flag) {
  __shared__ int cnt;
  if (threadIdx.x == 0) cnt = 0;
  __syncthreads();
  int ok = 0;
  for (int i = threadIdx.x; i < 1024; i += 256) {
    const int e = (x_raw[2 * i] >> 7) & 0xFF;
    if (e >= 117 && e <= 137) ok++;
  }
  atomicAdd(&cnt, ok);
  __syncthreads();
  if (threadIdx.x == 0) *flag = (cnt < 512) ? 1 : 0;
}

// ---------------------------------------------------------------------------
// Cast (mode 1: f32->bf16 RTNE; mode 0: raw copy). One launch for x + weights.
// blocks [0,4096): x -> xb; [4096,6144): Wq/Wk/Wv -> wqkv, Wo -> wob.
// ---------------------------------------------------------------------------
__device__ __forceinline__ void cast8(const void* src, u16* dst, int mode, size_t i) {
  union { u16 h[8]; uint4 v; } u;
  if (mode) {
    const float4* s = (const float4*)src + i * 2;
    const float4 a = s[0], b = s[1];
    u.h[0] = f32_to_bf16_rtne(a.x); u.h[1] = f32_to_bf16_rtne(a.y);
    u.h[2] = f32_to_bf16_rtne(a.z); u.h[3] = f32_to_bf16_rtne(a.w);
    u.h[4] = f32_to_bf16_rtne(b.x); u.h[5] = f32_to_bf16_rtne(b.y);
    u.h[6] = f32_to_bf16_rtne(b.z); u.h[7] = f32_to_bf16_rtne(b.w);
  } else {
    u.v = ((const uint4*)src)[i];
  }
  ((uint4*)dst)[i] = u.v;
}

__global__ __launch_bounds__(256)
void cast_all(const void* __restrict__ x,
              const void* __restrict__ wq, const void* __restrict__ wk,
              const void* __restrict__ wv, const void* __restrict__ wo,
              u16* __restrict__ xb, u16* __restrict__ wqkv,
              u16* __restrict__ wob, const int* __restrict__ flag) {
  const int mode = *flag;
  const int bid = blockIdx.x;
  if (bid < 4096) {
    cast8(x, xb, mode, (size_t)bid * 256 + threadIdx.x);
  } else {
    const size_t DD8 = (size_t)1024 * 1024 / 8;
    const int m = (bid - 4096) >> 9;
    const size_t i = ((size_t)((bid - 4096) & 511)) * 256 + threadIdx.x;
    const void* src = (m == 0) ? wq : (m == 1) ? wk : (m == 2) ? wv : wo;
    u16* dst = (m < 3) ? (wqkv + (size_t)m * DD8 * 8) : wob;
    cast8(src, dst, mode, i);
  }
}

// ---------------------------------------------------------------------------
// GEMM  C = A @ W^T + bias.  BM=BN=128, BK=64, 256 thr (2x2 waves), NITER=K/64.
// Pipelined: tile t+1 global->reg prefetch issues before tile t's MFMA section
// and stays in flight across the lgkm-only barriers (no vmcnt(0) drain).
// LDS layout XOR-swizzled: 16B granule g of row r lives at granule g^(r&7)
// -> frag reads 2-way (free), staging writes one lane per bank group.
// MODE 0 (QKV): band 0 -> o0 = qb (pre-scaled by SL2E); band 1 -> o1 = kb;
//               band 2 -> o2 = vtb[(b*16+h)*64+d][4096] (transposed V).
// MODE 1 (out): o0 = d_out, f32 if input-mode==1 else bf16.
// ---------------------------------------------------------------------------
template <int MODE>
__global__ __launch_bounds__(256)
void gemm_bt(const bf16* __restrict__ A, const bf16* __restrict__ W,
             const void* __restrict__ b0, const void* __restrict__ b1,
             const void* __restrict__ b2, void* __restrict__ o0,
             void* __restrict__ o1, void* __restrict__ o2,
             const int* __restrict__ flag, int M, int N, int K)
{
  __shared__ bf16 As[128 * 64];
  __shared__ bf16 Bs[128 * 64];

  const int mode = *flag;
  const int tid  = threadIdx.x;
  const int wave = tid >> 6, lane = tid & 63;
  const int quad = lane >> 4, l16 = lane & 15;
  const int wm   = wave >> 1, wn  = wave & 1;
  const int m0   = blockIdx.x * 128, n0 = blockIdx.y * 128;

  const int band = n0 >> 10;
  const void* bias = (band == 0) ? b0 : (band == 1) ? b1 : b2;

  // staging geometry: instr i covers rows wave*32+i*8 + srow, granule sg
  const int srow = lane >> 3;          // 0..7
  const int sg   = lane & 7;           // 16B granule 0..7
  const bf16* aSrc = A + (size_t)(m0 + wave * 32 + srow) * K + sg * 8;
  const bf16* wSrc = W + (size_t)(n0 + wave * 32 + srow) * K + sg * 8;
  bf16* aDst = As + (wave * 32 + srow) * 64 + ((sg ^ srow) * 8);
  bf16* wDst = Bs + (wave * 32 + srow) * 64 + ((sg ^ srow) * 8);

  const int niter = K >> 6;
  uint4 ra[2][4], rb[2][4];
#pragma unroll
  for (int i = 0; i < 4; ++i) {
    ra[0][i] = *(const uint4*)(aSrc + (size_t)i * 8 * K);
    rb[0][i] = *(const uint4*)(wSrc + (size_t)i * 8 * K);
  }
  aSrc += 64; wSrc += 64;

  f32x4 acc[4][4] = {};

  // frag-read LDS offsets (swizzled); row&7 == l16&7 for all frag rows
  const int arow[4] = { (wm * 64 + 0 * 16 + l16) * 64, (wm * 64 + 1 * 16 + l16) * 64,
                        (wm * 64 + 2 * 16 + l16) * 64, (wm * 64 + 3 * 16 + l16) * 64 };
  const int brow[4] = { (wn * 64 + 0 * 16 + l16) * 64, (wn * 64 + 1 * 16 + l16) * 64,
                        (wn * 64 + 2 * 16 + l16) * 64, (wn * 64 + 3 * 16 + l16) * 64 };
  const int r7 = l16 & 7;

#pragma unroll 2
  for (int t = 0; t < niter; ++t) {
    const int cur = t & 1, nxt = cur ^ 1;
    if (t) barrier_lgkm();                    // all waves done reading prev tile
#pragma unroll
    for (int i = 0; i < 4; ++i) {             // compiler waits vmcnt for ra/rb here
      *(uint4*)(aDst + i * 512) = ra[cur][i];
      *(uint4*)(wDst + i * 512) = rb[cur][i];
    }
    barrier_lgkm();                           // writes visible; prefetch NOT drained
    if (t + 1 < niter) {
#pragma unroll
      for (int i = 0; i < 4; ++i) {
        ra[nxt][i] = *(const uint4*)(aSrc + (size_t)i * 8 * K);
        rb[nxt][i] = *(const uint4*)(wSrc + (size_t)i * 8 * K);
      }
      aSrc += 64; wSrc += 64;
    }
#pragma unroll
    for (int kk = 0; kk < 2; ++kk) {
      bf16x8 af[4], bw[4];
#pragma unroll
      for (int mt = 0; mt < 4; ++mt)
        af[mt] = *(const bf16x8*)(As + arow[mt] + (((kk * 4 + quad) ^ r7) * 8));
#pragma unroll
      for (int nt = 0; nt < 4; ++nt)
        bw[nt] = *(const bf16x8*)(Bs + brow[nt] + (((kk * 4 + quad) ^ r7) * 8));
#pragma unroll
      for (int mt = 0; mt < 4; ++mt)
#pragma unroll
        for (int nt = 0; nt < 4; ++nt)
          acc[mt][nt] = MFMA(af[mt], bw[nt], acc[mt][nt]);
    }
  }

  // epilogue: C/D layout col = lane&15, row = quad*4 + reg
#pragma unroll
  for (int nt = 0; nt < 4; ++nt) {
    const int col = n0 + wn * 64 + nt * 16 + l16;
    const int cl  = col & 1023;
    const float bv = mode ? ((const float*)bias)[cl]
                          : bf16_to_f32(((const u16*)bias)[cl]);
#pragma unroll
    for (int mt = 0; mt < 4; ++mt) {
      const int rbase = m0 + wm * 64 + mt * 16 + quad * 4;
      if (MODE == 1) {
#pragma unroll
        for (int r = 0; r < 4; ++r) {
          const float val = acc[mt][nt][r] + bv;
          const size_t idx = (size_t)(rbase + r) * N + col;
          if (mode) ((float*)o0)[idx] = val;
          else      ((u16*)o0)[idx]   = f32_to_bf16_rtne(val);
        }
      } else if (band == 2) {
        // transposed V: vt[(b*16+h)*64 + d][token], 4 consecutive tokens packed
        const int hh = cl >> 6, dd = cl & 63;
        const int bb = rbase >> 12, tl = rbase & 4095;
        u16* dst = (u16*)o2 + ((size_t)((bb * 16 + hh) * 64 + dd)) * 4096 + tl;
        uint2 pk;
        pk.x = pk2bf(acc[mt][nt][0] + bv, acc[mt][nt][1] + bv);
        pk.y = pk2bf(acc[mt][nt][2] + bv, acc[mt][nt][3] + bv);
        *(uint2*)dst = pk;
      } else {
        u16* dst = (u16*)((band == 0) ? o0 : o1);
        const float sc = (band == 0) ? SL2E : 1.0f;
#pragma unroll
        for (int r = 0; r < 4; ++r)
          dst[(size_t)(rbase + r) * 1024 + cl] =
              f32_to_bf16_rtne((acc[mt][nt][r] + bv) * sc);
      }
    }
  }
}

// ---------------------------------------------------------------------------
// Sliding-window attention, S^T formulation, fixed-max softmax. (as R4)
// grid = 1024: bid = qt*256 + g, g = (b<<7)|(c<<4)|h, qt 0..3 (128 q/block).
// ---------------------------------------------------------------------------
__global__ __launch_bounds__(256)
void attn_swin(const bf16* __restrict__ qb, const bf16* __restrict__ kb,
               const bf16* __restrict__ vtb, u16* __restrict__ ctx)
{
  __shared__ __align__(16) bf16 Ks[64 * 72];
  __shared__ __align__(16) bf16 Vts[64 * 72];

  int bid = blockIdx.x;
  const int g  = bid & 255, qt = bid >> 8;
  const int h  = g & 15, c = (g >> 4) & 7, b = g >> 7;

  const int tid  = threadIdx.x;
  const int w    = tid >> 6, lane = tid & 63;
  const int quad = lane >> 4, l16 = lane & 15;

  const int tq0  = c * 512 + qt * 128;
  const int hoff = h * 64;
  const int kstart = (c == 0) ? 0 : (c - 1) * 512;
  const int nkt    = (c == 0) ? 8 : 16;

  // ---- Q B-frags straight from global (no LDS, no barrier) ----
  bf16x8 qf[2][2];
#pragma unroll
  for (int u = 0; u < 2; ++u) {
    const bf16* qr = qb + ((size_t)(b * 4096 + tq0 + w * 32 + u * 16 + l16)) * 1024 + hoff;
    qf[u][0] = *(const bf16x8*)(qr + quad * 8);
    qf[u][1] = *(const bf16x8*)(qr + 32 + quad * 8);
  }

  // ---- staging addresses (hoisted) ----
  const int m    = tid >> 2;            // LDS row 0..63
  const int cseg = (tid & 3) * 16;      // 32B column segment
  const int sig  = (((m >> 4) & 1) << 5) | (((m >> 2) & 3) << 3)
                 | (((m >> 5) & 1) << 2) | (m & 3);
  const bf16* kgp = kb + ((size_t)(b * 4096 + kstart + sig)) * 1024 + hoff + cseg;
  const bf16* vgp = vtb + ((size_t)((b * 16 + h) * 64 + m)) * 4096 + kstart + cseg;
  bf16* kdst = Ks  + m * 72 + cseg;
  bf16* vdst = Vts + m * 72 + cseg;

  float l_i[2] = {0.f, 0.f};
  f32x4 o[2][4] = {};

  uint4 ka0 = *(const uint4*)(kgp), ka1 = *(const uint4*)(kgp + 8);
  uint4 va0 = *(const uint4*)(vgp), va1 = *(const uint4*)(vgp + 8);
  kgp += (size_t)64 * 1024; vgp += 64;

  for (int t = 0; t < nkt; ++t) {
    uint4 kb0, kb1, vb0, vb1;
    if (t + 1 < nkt) {
      kb0 = *(const uint4*)(kgp); kb1 = *(const uint4*)(kgp + 8);
      vb0 = *(const uint4*)(vgp); vb1 = *(const uint4*)(vgp + 8);
      kgp += (size_t)64 * 1024; vgp += 64;
    }
    *(uint4*)(kdst) = ka0; *(uint4*)(kdst + 8) = ka1;
    *(uint4*)(vdst) = va0; *(uint4*)(vdst + 8) = va1;
    barrier_lgkm();

    f32x4 s[2][4] = {};
#pragma unroll
    for (int kt = 0; kt < 4; ++kt) {
      const bf16* kr = Ks + (kt * 16 + l16) * 72;
      bf16x8 kf0 = *(const bf16x8*)(kr + quad * 8);
      bf16x8 kf1 = *(const bf16x8*)(kr + 32 + quad * 8);
      s[0][kt] = MFMA(kf0, qf[0][0], s[0][kt]);
      s[0][kt] = MFMA(kf1, qf[0][1], s[0][kt]);
      s[1][kt] = MFMA(kf0, qf[1][0], s[1][kt]);
      s[1][kt] = MFMA(kf1, qf[1][1], s[1][kt]);
    }

    typedef union { u32 d[4]; bf16x8 v; } fragu;
    fragu pf[2][2];
#pragma unroll
    for (int u = 0; u < 2; ++u) {
      float rs = 0.f;
#pragma unroll
      for (int kt = 0; kt < 4; ++kt)
#pragma unroll
        for (int r = 0; r < 4; ++r) {
          const float p = __builtin_amdgcn_exp2f(s[u][kt][r]);
          s[u][kt][r] = p;
          rs += p;
        }
      rs += __shfl_xor(rs, 16);
      rs += __shfl_xor(rs, 32);
      l_i[u] += rs;
#pragma unroll
      for (int hh = 0; hh < 2; ++hh)
#pragma unroll
        for (int dw = 0; dw < 4; ++dw) {
          const int kt = 2 * (dw >> 1) + hh, r0 = 2 * (dw & 1);
          pf[u][hh].d[dw] = pk2bf(s[u][kt][r0], s[u][kt][r0 + 1]);
        }
    }

#pragma unroll
    for (int dt = 0; dt < 4; ++dt) {
      const bf16* vr = Vts + (dt * 16 + l16) * 72;
      bf16x8 vf0 = *(const bf16x8*)(vr + quad * 8);
      bf16x8 vf1 = *(const bf16x8*)(vr + 32 + quad * 8);
      o[0][dt] = MFMA(vf0, pf[0][0].v, o[0][dt]);
      o[0][dt] = MFMA(vf1, pf[0][1].v, o[0][dt]);
      o[1][dt] = MFMA(vf0, pf[1][0].v, o[1][dt]);
      o[1][dt] = MFMA(vf1, pf[1][1].v, o[1][dt]);
    }
    barrier_lgkm();

    ka0 = kb0; ka1 = kb1; va0 = vb0; va1 = vb1;
  }

#pragma unroll
  for (int u = 0; u < 2; ++u) {
    const float inv = 1.0f / l_i[u];
    const int qrow = tq0 + w * 32 + u * 16 + l16;
    u16* crow = ctx + ((size_t)(b * 4096 + qrow)) * 1024 + hoff;
#pragma unroll
    for (int dt = 0; dt < 4; ++dt) {
      uint2 pk;
      pk.x = pk2bf(o[u][dt][0] * inv, o[u][dt][1] * inv);
      pk.y = pk2bf(o[u][dt][2] * inv, o[u][dt][3] * inv);
      *(uint2*)(crow + dt * 16 + quad * 4) = pk;
    }
  }
}

// ---------------------------------------------------------------------------
extern "C" void kernel_launch(void* const* d_in, const int* in_sizes, int n_in,
                              void* d_out, int out_size, void* d_ws, size_t ws_size,
                              hipStream_t stream) {
  const void* x  = d_in[0];
  const void* Wq = d_in[1];
  const void* bq = d_in[2];
  const void* Wk = d_in[3];
  const void* bk = d_in[4];
  const void* Wv = d_in[5];
  const void* bv = d_in[6];
  const void* Wo = d_in[7];
  const void* bo = d_in[8];

  const size_t MD = (size_t)8192 * 1024;   // [B*L, D] elements
  const size_t DD = (size_t)1024 * 1024;   // [D, D] elements

  char* ws = (char*)d_ws;
  int*  flag  = (int*)ws;                     ws += 256;
  u16*  xb    = (u16*)ws;                     ws += MD * 2;
  u16*  Wqkvb = (u16*)ws;                     ws += 3 * DD * 2;
  u16*  Wob   = (u16*)ws;                     ws += DD * 2;
  u16*  qbuf  = (u16*)ws;                     ws += MD * 2;
  u16*  kbuf  = (u16*)ws;                     ws += MD * 2;
  u16*  vtb   = (u16*)ws;                     ws += MD * 2;
  u16*  ctx   = (u16*)ws;                     // + MD*2  (~88 MB total)

  detect_mode<<<dim3(1), dim3(256), 0, stream>>>((const u16*)x, flag);
  cast_all<<<dim3(6144), dim3(256), 0, stream>>>(x, Wq, Wk, Wv, Wo,
                                                 xb, Wqkvb, Wob, flag);

  // fused QKV projection with splitting epilogue (q scaled, v transposed)
  gemm_bt<0><<<dim3(64, 24), dim3(256), 0, stream>>>(
      (const bf16*)xb, (const bf16*)Wqkvb, bq, bk, bv,
      qbuf, kbuf, vtb, flag, 8192, 3072, 1024);

  attn_swin<<<dim3(1024), dim3(256), 0, stream>>>(
      (const bf16*)qbuf, (const bf16*)kbuf, (const bf16*)vtb, ctx);

  gemm_bt<1><<<dim3(64, 8), dim3(256), 0, stream>>>(
      (const bf16*)ctx, (const bf16*)Wob, bo, bo, bo,
      d_out, nullptr, nullptr, flag, 8192, 1024, 1024);
}

// Round 6
// 253.975 us; speedup vs baseline: 1.9666x; 1.9666x over previous
//
#include <hip/hip_runtime.h>
#include <hip/hip_bf16.h>

typedef __hip_bfloat16 bf16;
typedef __attribute__((ext_vector_type(8))) short bf16x8;   // 8 bf16 = 4 VGPRs (MFMA A/B frag)
typedef __attribute__((ext_vector_type(4))) float f32x4;    // MFMA C/D frag
typedef unsigned int u32;
typedef unsigned short u16;

#define MFMA(a,b,c) __builtin_amdgcn_mfma_f32_16x16x32_bf16((a),(b),(c),0,0,0)

__device__ __forceinline__ u16 f32_to_bf16_rtne(float f) {
  u32 b = __builtin_bit_cast(u32, f);
  b += 0x7FFFu + ((b >> 16) & 1u);
  return (u16)(b >> 16);
}
__device__ __forceinline__ float bf16_to_f32(u16 h) {
  return __builtin_bit_cast(float, (u32)h << 16);
}
// pack two f32 -> (lo: a, hi: b) bf16 pair, RTNE; v_perm does the byte-select
__device__ __forceinline__ u32 pk2bf(float a, float b) {
  u32 ua = __builtin_bit_cast(u32, a); ua += 0x7FFFu + ((ua >> 16) & 1u);
  u32 ub = __builtin_bit_cast(u32, b); ub += 0x7FFFu + ((ub >> 16) & 1u);
  return __builtin_amdgcn_perm(ub, ua, 0x07060302u);
}

// lgkm-only barrier: LDS ops drained, but outstanding global->reg prefetch
// loads stay IN FLIGHT across the barrier (no vmcnt(0) drain).
__device__ __forceinline__ void barrier_lgkm() {
  asm volatile("s_waitcnt lgkmcnt(0)\n\ts_barrier" ::: "memory");
}

static constexpr float SL2E = 0.125f * 1.44269504f;  // 1/sqrt(dh) * log2(e)

// ---------------------------------------------------------------------------
// Detect input dtype. mode=1: f32 inputs. mode=0: bf16 inputs.
// ---------------------------------------------------------------------------
__global__ void detect_mode(const u16* __restrict__ x_raw, int* __restrict__ flag) {
  __shared__ int cnt;
  if (threadIdx.x == 0) cnt = 0;
  __syncthreads();
  int ok = 0;
  for (int i = threadIdx.x; i < 1024; i += 256) {
    const int e = (x_raw[2 * i] >> 7) & 0xFF;
    if (e >= 117 && e <= 137) ok++;
  }
  atomicAdd(&cnt, ok);
  __syncthreads();
  if (threadIdx.x == 0) *flag = (cnt < 512) ? 1 : 0;
}

// ---------------------------------------------------------------------------
// Cast (mode 1: f32->bf16 RTNE; mode 0: raw copy). One launch for x + weights.
// ---------------------------------------------------------------------------
__device__ __forceinline__ void cast8(const void* src, u16* dst, int mode, size_t i) {
  union { u16 h[8]; uint4 v; } u;
  if (mode) {
    const float4* s = (const float4*)src + i * 2;
    const float4 a = s[0], b = s[1];
    u.h[0] = f32_to_bf16_rtne(a.x); u.h[1] = f32_to_bf16_rtne(a.y);
    u.h[2] = f32_to_bf16_rtne(a.z); u.h[3] = f32_to_bf16_rtne(a.w);
    u.h[4] = f32_to_bf16_rtne(b.x); u.h[5] = f32_to_bf16_rtne(b.y);
    u.h[6] = f32_to_bf16_rtne(b.z); u.h[7] = f32_to_bf16_rtne(b.w);
  } else {
    u.v = ((const uint4*)src)[i];
  }
  ((uint4*)dst)[i] = u.v;
}

__global__ __launch_bounds__(256)
void cast_all(const void* __restrict__ x,
              const void* __restrict__ wq, const void* __restrict__ wk,
              const void* __restrict__ wv, const void* __restrict__ wo,
              u16* __restrict__ xb, u16* __restrict__ wqkv,
              u16* __restrict__ wob, const int* __restrict__ flag) {
  const int mode = *flag;
  const int bid = blockIdx.x;
  if (bid < 4096) {
    cast8(x, xb, mode, (size_t)bid * 256 + threadIdx.x);
  } else {
    const size_t DD8 = (size_t)1024 * 1024 / 8;
    const int m = (bid - 4096) >> 9;
    const size_t i = ((size_t)((bid - 4096) & 511)) * 256 + threadIdx.x;
    const void* src = (m == 0) ? wq : (m == 1) ? wk : (m == 2) ? wv : wo;
    u16* dst = (m < 3) ? (wqkv + (size_t)m * DD8 * 8) : wob;
    cast8(src, dst, mode, i);
  }
}

// ---------------------------------------------------------------------------
// GEMM  C = A @ W^T + bias.  BM=BN=128, BK=64, 256 thr (2x2 waves).
// Pipelined with NAMED prefetch registers (no arrays -> no scratch): tile t's
// ds_write consumes a0..w3, then tile t+1's global loads re-fill the same
// registers and stay in flight across the lgkm-only barriers + MFMA section.
// LDS XOR-swizzled: 16B granule g of row r lives at g^(r&7) -> frag reads
// 2-way (free, conflicts=0 verified R5), staging writes conflict-free.
// MODE 0 (QKV): band 0 -> o0 = qb (pre-scaled by SL2E); band 1 -> o1 = kb;
//               band 2 -> o2 = vtb[(b*16+h)*64+d][4096] (transposed V).
// MODE 1 (out): o0 = d_out, f32 if input-mode==1 else bf16.
// ---------------------------------------------------------------------------
template <int MODE>
__global__ __launch_bounds__(256)
void gemm_bt(const bf16* __restrict__ A, const bf16* __restrict__ W,
             const void* __restrict__ b0, const void* __restrict__ b1,
             const void* __restrict__ b2, void* __restrict__ o0,
             void* __restrict__ o1, void* __restrict__ o2,
             const int* __restrict__ flag, int M, int N, int K)
{
  __shared__ bf16 As[128 * 64];
  __shared__ bf16 Bs[128 * 64];

  const int mode = *flag;
  const int tid  = threadIdx.x;
  const int wave = tid >> 6, lane = tid & 63;
  const int quad = lane >> 4, l16 = lane & 15;
  const int wm   = wave >> 1, wn  = wave & 1;
  const int m0   = blockIdx.x * 128, n0 = blockIdx.y * 128;

  const int band = n0 >> 10;
  const void* bias = (band == 0) ? b0 : (band == 1) ? b1 : b2;

  // staging geometry: store i covers row wave*32 + i*8 + srow, granule sg
  const int srow = lane >> 3;          // 0..7
  const int sg   = lane & 7;           // 16B granule 0..7
  const size_t rgs = (size_t)8 * K;    // 8-row group stride in A/W
  const bf16* aSrc = A + (size_t)(m0 + wave * 32 + srow) * K + sg * 8;
  const bf16* wSrc = W + (size_t)(n0 + wave * 32 + srow) * K + sg * 8;
  bf16* aDst = As + (wave * 32 + srow) * 64 + ((sg ^ srow) * 8);
  bf16* wDst = Bs + (wave * 32 + srow) * 64 + ((sg ^ srow) * 8);

  const int niter = K >> 6;

  // prefetch tile 0 (named registers only)
  uint4 a0 = *(const uint4*)(aSrc);
  uint4 a1 = *(const uint4*)(aSrc + rgs);
  uint4 a2 = *(const uint4*)(aSrc + 2 * rgs);
  uint4 a3 = *(const uint4*)(aSrc + 3 * rgs);
  uint4 w0 = *(const uint4*)(wSrc);
  uint4 w1 = *(const uint4*)(wSrc + rgs);
  uint4 w2 = *(const uint4*)(wSrc + 2 * rgs);
  uint4 w3 = *(const uint4*)(wSrc + 3 * rgs);
  aSrc += 64; wSrc += 64;

  f32x4 acc[4][4] = {};

  const int arow[4] = { (wm * 64 + 0 * 16 + l16) * 64, (wm * 64 + 1 * 16 + l16) * 64,
                        (wm * 64 + 2 * 16 + l16) * 64, (wm * 64 + 3 * 16 + l16) * 64 };
  const int brow[4] = { (wn * 64 + 0 * 16 + l16) * 64, (wn * 64 + 1 * 16 + l16) * 64,
                        (wn * 64 + 2 * 16 + l16) * 64, (wn * 64 + 3 * 16 + l16) * 64 };
  const int r7 = l16 & 7;

  for (int t = 0; t < niter; ++t) {
    if (t) barrier_lgkm();                 // all waves done reading prev tile
    // ds_write consumes the prefetch regs (compiler inserts the vmcnt wait)
    *(uint4*)(aDst)        = a0;
    *(uint4*)(aDst + 512)  = a1;
    *(uint4*)(aDst + 1024) = a2;
    *(uint4*)(aDst + 1536) = a3;
    *(uint4*)(wDst)        = w0;
    *(uint4*)(wDst + 512)  = w1;
    *(uint4*)(wDst + 1024) = w2;
    *(uint4*)(wDst + 1536) = w3;
    barrier_lgkm();                        // writes visible; vmem NOT drained
    if (t + 1 < niter) {                   // re-fill the same named regs
      a0 = *(const uint4*)(aSrc);
      a1 = *(const uint4*)(aSrc + rgs);
      a2 = *(const uint4*)(aSrc + 2 * rgs);
      a3 = *(const uint4*)(aSrc + 3 * rgs);
      w0 = *(const uint4*)(wSrc);
      w1 = *(const uint4*)(wSrc + rgs);
      w2 = *(const uint4*)(wSrc + 2 * rgs);
      w3 = *(const uint4*)(wSrc + 3 * rgs);
      aSrc += 64; wSrc += 64;
    }
#pragma unroll
    for (int kk = 0; kk < 2; ++kk) {
      bf16x8 af[4], bw[4];
#pragma unroll
      for (int mt = 0; mt < 4; ++mt)
        af[mt] = *(const bf16x8*)(As + arow[mt] + (((kk * 4 + quad) ^ r7) * 8));
#pragma unroll
      for (int nt = 0; nt < 4; ++nt)
        bw[nt] = *(const bf16x8*)(Bs + brow[nt] + (((kk * 4 + quad) ^ r7) * 8));
#pragma unroll
      for (int mt = 0; mt < 4; ++mt)
#pragma unroll
        for (int nt = 0; nt < 4; ++nt)
          acc[mt][nt] = MFMA(af[mt], bw[nt], acc[mt][nt]);
    }
  }

  // epilogue: C/D layout col = lane&15, row = quad*4 + reg
#pragma unroll
  for (int nt = 0; nt < 4; ++nt) {
    const int col = n0 + wn * 64 + nt * 16 + l16;
    const int cl  = col & 1023;
    const float bv = mode ? ((const float*)bias)[cl]
                          : bf16_to_f32(((const u16*)bias)[cl]);
#pragma unroll
    for (int mt = 0; mt < 4; ++mt) {
      const int rbase = m0 + wm * 64 + mt * 16 + quad * 4;
      if (MODE == 1) {
#pragma unroll
        for (int r = 0; r < 4; ++r) {
          const float val = acc[mt][nt][r] + bv;
          const size_t idx = (size_t)(rbase + r) * N + col;
          if (mode) ((float*)o0)[idx] = val;
          else      ((u16*)o0)[idx]   = f32_to_bf16_rtne(val);
        }
      } else if (band == 2) {
        // transposed V: vt[(b*16+h)*64 + d][token], 4 consecutive tokens packed
        const int hh = cl >> 6, dd = cl & 63;
        const int bb = rbase >> 12, tl = rbase & 4095;
        u16* dst = (u16*)o2 + ((size_t)((bb * 16 + hh) * 64 + dd)) * 4096 + tl;
        uint2 pk;
        pk.x = pk2bf(acc[mt][nt][0] + bv, acc[mt][nt][1] + bv);
        pk.y = pk2bf(acc[mt][nt][2] + bv, acc[mt][nt][3] + bv);
        *(uint2*)dst = pk;
      } else {
        u16* dst = (u16*)((band == 0) ? o0 : o1);
        const float sc = (band == 0) ? SL2E : 1.0f;
#pragma unroll
        for (int r = 0; r < 4; ++r)
          dst[(size_t)(rbase + r) * 1024 + cl] =
              f32_to_bf16_rtne((acc[mt][nt][r] + bv) * sc);
      }
    }
  }
}

// ---------------------------------------------------------------------------
// Sliding-window attention, S^T formulation, fixed-max softmax. (as R4)
// grid = 1024: bid = qt*256 + g, g = (b<<7)|(c<<4)|h, qt 0..3 (128 q/block).
// ---------------------------------------------------------------------------
__global__ __launch_bounds__(256)
void attn_swin(const bf16* __restrict__ qb, const bf16* __restrict__ kb,
               const bf16* __restrict__ vtb, u16* __restrict__ ctx)
{
  __shared__ __align__(16) bf16 Ks[64 * 72];
  __shared__ __align__(16) bf16 Vts[64 * 72];

  int bid = blockIdx.x;
  const int g  = bid & 255, qt = bid >> 8;
  const int h  = g & 15, c = (g >> 4) & 7, b = g >> 7;

  const int tid  = threadIdx.x;
  const int w    = tid >> 6, lane = tid & 63;
  const int quad = lane >> 4, l16 = lane & 15;

  const int tq0  = c * 512 + qt * 128;
  const int hoff = h * 64;
  const int kstart = (c == 0) ? 0 : (c - 1) * 512;
  const int nkt    = (c == 0) ? 8 : 16;

  // ---- Q B-frags straight from global (no LDS, no barrier) ----
  bf16x8 qf[2][2];
#pragma unroll
  for (int u = 0; u < 2; ++u) {
    const bf16* qr = qb + ((size_t)(b * 4096 + tq0 + w * 32 + u * 16 + l16)) * 1024 + hoff;
    qf[u][0] = *(const bf16x8*)(qr + quad * 8);
    qf[u][1] = *(const bf16x8*)(qr + 32 + quad * 8);
  }

  // ---- staging addresses (hoisted) ----
  const int m    = tid >> 2;            // LDS row 0..63
  const int cseg = (tid & 3) * 16;      // 32B column segment
  const int sig  = (((m >> 4) & 1) << 5) | (((m >> 2) & 3) << 3)
                 | (((m >> 5) & 1) << 2) | (m & 3);
  const bf16* kgp = kb + ((size_t)(b * 4096 + kstart + sig)) * 1024 + hoff + cseg;
  const bf16* vgp = vtb + ((size_t)((b * 16 + h) * 64 + m)) * 4096 + kstart + cseg;
  bf16* kdst = Ks  + m * 72 + cseg;
  bf16* vdst = Vts + m * 72 + cseg;

  float l_i[2] = {0.f, 0.f};
  f32x4 o[2][4] = {};

  uint4 ka0 = *(const uint4*)(kgp), ka1 = *(const uint4*)(kgp + 8);
  uint4 va0 = *(const uint4*)(vgp), va1 = *(const uint4*)(vgp + 8);
  kgp += (size_t)64 * 1024; vgp += 64;

  for (int t = 0; t < nkt; ++t) {
    uint4 kb0, kb1, vb0, vb1;
    if (t + 1 < nkt) {
      kb0 = *(const uint4*)(kgp); kb1 = *(const uint4*)(kgp + 8);
      vb0 = *(const uint4*)(vgp); vb1 = *(const uint4*)(vgp + 8);
      kgp += (size_t)64 * 1024; vgp += 64;
    }
    *(uint4*)(kdst) = ka0; *(uint4*)(kdst + 8) = ka1;
    *(uint4*)(vdst) = va0; *(uint4*)(vdst + 8) = va1;
    barrier_lgkm();

    f32x4 s[2][4] = {};
#pragma unroll
    for (int kt = 0; kt < 4; ++kt) {
      const bf16* kr = Ks + (kt * 16 + l16) * 72;
      bf16x8 kf0 = *(const bf16x8*)(kr + quad * 8);
      bf16x8 kf1 = *(const bf16x8*)(kr + 32 + quad * 8);
      s[0][kt] = MFMA(kf0, qf[0][0], s[0][kt]);
      s[0][kt] = MFMA(kf1, qf[0][1], s[0][kt]);
      s[1][kt] = MFMA(kf0, qf[1][0], s[1][kt]);
      s[1][kt] = MFMA(kf1, qf[1][1], s[1][kt]);
    }

    typedef union { u32 d[4]; bf16x8 v; } fragu;
    fragu pf[2][2];
#pragma unroll
    for (int u = 0; u < 2; ++u) {
      float rs = 0.f;
#pragma unroll
      for (int kt = 0; kt < 4; ++kt)
#pragma unroll
        for (int r = 0; r < 4; ++r) {
          const float p = __builtin_amdgcn_exp2f(s[u][kt][r]);
          s[u][kt][r] = p;
          rs += p;
        }
      rs += __shfl_xor(rs, 16);
      rs += __shfl_xor(rs, 32);
      l_i[u] += rs;
#pragma unroll
      for (int hh = 0; hh < 2; ++hh)
#pragma unroll
        for (int dw = 0; dw < 4; ++dw) {
          const int kt = 2 * (dw >> 1) + hh, r0 = 2 * (dw & 1);
          pf[u][hh].d[dw] = pk2bf(s[u][kt][r0], s[u][kt][r0 + 1]);
        }
    }

#pragma unroll
    for (int dt = 0; dt < 4; ++dt) {
      const bf16* vr = Vts + (dt * 16 + l16) * 72;
      bf16x8 vf0 = *(const bf16x8*)(vr + quad * 8);
      bf16x8 vf1 = *(const bf16x8*)(vr + 32 + quad * 8);
      o[0][dt] = MFMA(vf0, pf[0][0].v, o[0][dt]);
      o[0][dt] = MFMA(vf1, pf[0][1].v, o[0][dt]);
      o[1][dt] = MFMA(vf0, pf[1][0].v, o[1][dt]);
      o[1][dt] = MFMA(vf1, pf[1][1].v, o[1][dt]);
    }
    barrier_lgkm();

    ka0 = kb0; ka1 = kb1; va0 = vb0; va1 = vb1;
  }

#pragma unroll
  for (int u = 0; u < 2; ++u) {
    const float inv = 1.0f / l_i[u];
    const int qrow = tq0 + w * 32 + u * 16 + l16;
    u16* crow = ctx + ((size_t)(b * 4096 + qrow)) * 1024 + hoff;
#pragma unroll
    for (int dt = 0; dt < 4; ++dt) {
      uint2 pk;
      pk.x = pk2bf(o[u][dt][0] * inv, o[u][dt][1] * inv);
      pk.y = pk2bf(o[u][dt][2] * inv, o[u][dt][3] * inv);
      *(uint2*)(crow + dt * 16 + quad * 4) = pk;
    }
  }
}

// ---------------------------------------------------------------------------
extern "C" void kernel_launch(void* const* d_in, const int* in_sizes, int n_in,
                              void* d_out, int out_size, void* d_ws, size_t ws_size,
                              hipStream_t stream) {
  const void* x  = d_in[0];
  const void* Wq = d_in[1];
  const void* bq = d_in[2];
  const void* Wk = d_in[3];
  const void* bk = d_in[4];
  const void* Wv = d_in[5];
  const void* bv = d_in[6];
  const void* Wo = d_in[7];
  const void* bo = d_in[8];

  const size_t MD = (size_t)8192 * 1024;   // [B*L, D] elements
  const size_t DD = (size_t)1024 * 1024;   // [D, D] elements

  char* ws = (char*)d_ws;
  int*  flag  = (int*)ws;                     ws += 256;
  u16*  xb    = (u16*)ws;                     ws += MD * 2;
  u16*  Wqkvb = (u16*)ws;                     ws += 3 * DD * 2;
  u16*  Wob   = (u16*)ws;                     ws += DD * 2;
  u16*  qbuf  = (u16*)ws;                     ws += MD * 2;
  u16*  kbuf  = (u16*)ws;                     ws += MD * 2;
  u16*  vtb   = (u16*)ws;                     ws += MD * 2;
  u16*  ctx   = (u16*)ws;                     // + MD*2  (~88 MB total)

  detect_mode<<<dim3(1), dim3(256), 0, stream>>>((const u16*)x, flag);
  cast_all<<<dim3(6144), dim3(256), 0, stream>>>(x, Wq, Wk, Wv, Wo,
                                                 xb, Wqkvb, Wob, flag);

  // fused QKV projection with splitting epilogue (q scaled, v transposed)
  gemm_bt<0><<<dim3(64, 24), dim3(256), 0, stream>>>(
      (const bf16*)xb, (const bf16*)Wqkvb, bq, bk, bv,
      qbuf, kbuf, vtb, flag, 8192, 3072, 1024);

  attn_swin<<<dim3(1024), dim3(256), 0, stream>>>(
      (const bf16*)qbuf, (const bf16*)kbuf, (const bf16*)vtb, ctx);

  gemm_bt<1><<<dim3(64, 8), dim3(256), 0, stream>>>(
      (const bf16*)ctx, (const bf16*)Wob, bo, bo, bo,
      d_out, nullptr, nullptr, flag, 8192, 1024, 1024);
}

// Round 7
// 238.569 us; speedup vs baseline: 2.0936x; 1.0646x over previous
//
#include <hip/hip_runtime.h>
#include <hip/hip_bf16.h>

typedef __hip_bfloat16 bf16;
typedef __attribute__((ext_vector_type(8))) short bf16x8;   // 8 bf16 = 4 VGPRs (MFMA A/B frag)
typedef __attribute__((ext_vector_type(4))) float f32x4;    // MFMA C/D frag
typedef unsigned int u32;
typedef unsigned short u16;

#define MFMA(a,b,c) __builtin_amdgcn_mfma_f32_16x16x32_bf16((a),(b),(c),0,0,0)

__device__ __forceinline__ u16 f32_to_bf16_rtne(float f) {
  u32 b = __builtin_bit_cast(u32, f);
  b += 0x7FFFu + ((b >> 16) & 1u);
  return (u16)(b >> 16);
}
__device__ __forceinline__ float bf16_to_f32(u16 h) {
  return __builtin_bit_cast(float, (u32)h << 16);
}
// pack two f32 -> bf16 pair, RTNE (epilogue paths)
__device__ __forceinline__ u32 pk2bf(float a, float b) {
  u32 ua = __builtin_bit_cast(u32, a); ua += 0x7FFFu + ((ua >> 16) & 1u);
  u32 ub = __builtin_bit_cast(u32, b); ub += 0x7FFFu + ((ub >> 16) & 1u);
  return __builtin_amdgcn_perm(ub, ua, 0x07060302u);
}
// pack two f32 -> bf16 pair, RTZ (P-matrix hot path: 1 v_perm)
__device__ __forceinline__ u32 pk2bf_rtz(float a, float b) {
  return __builtin_amdgcn_perm(__builtin_bit_cast(u32, b),
                               __builtin_bit_cast(u32, a), 0x07060302u);
}

// lgkm-only barrier: LDS ops drained, but outstanding global->reg prefetch
// loads stay IN FLIGHT across the barrier (no vmcnt(0) drain).
__device__ __forceinline__ void barrier_lgkm() {
  asm volatile("s_waitcnt lgkmcnt(0)\n\ts_barrier" ::: "memory");
}

static constexpr float SL2E = 0.125f * 1.44269504f;  // 1/sqrt(dh) * log2(e)

// ---------------------------------------------------------------------------
// Detect input dtype. mode=1: f32 inputs. mode=0: bf16 inputs.
// ---------------------------------------------------------------------------
__global__ void detect_mode(const u16* __restrict__ x_raw, int* __restrict__ flag) {
  __shared__ int cnt;
  if (threadIdx.x == 0) cnt = 0;
  __syncthreads();
  int ok = 0;
  for (int i = threadIdx.x; i < 1024; i += 256) {
    const int e = (x_raw[2 * i] >> 7) & 0xFF;
    if (e >= 117 && e <= 137) ok++;
  }
  atomicAdd(&cnt, ok);
  __syncthreads();
  if (threadIdx.x == 0) *flag = (cnt < 512) ? 1 : 0;
}

// ---------------------------------------------------------------------------
// Cast (mode 1: f32->bf16 RTNE; mode 0: raw copy). One launch for x + weights.
// ---------------------------------------------------------------------------
__device__ __forceinline__ void cast8(const void* src, u16* dst, int mode, size_t i) {
  union { u16 h[8]; uint4 v; } u;
  if (mode) {
    const float4* s = (const float4*)src + i * 2;
    const float4 a = s[0], b = s[1];
    u.h[0] = f32_to_bf16_rtne(a.x); u.h[1] = f32_to_bf16_rtne(a.y);
    u.h[2] = f32_to_bf16_rtne(a.z); u.h[3] = f32_to_bf16_rtne(a.w);
    u.h[4] = f32_to_bf16_rtne(b.x); u.h[5] = f32_to_bf16_rtne(b.y);
    u.h[6] = f32_to_bf16_rtne(b.z); u.h[7] = f32_to_bf16_rtne(b.w);
  } else {
    u.v = ((const uint4*)src)[i];
  }
  ((uint4*)dst)[i] = u.v;
}

__global__ __launch_bounds__(256)
void cast_all(const void* __restrict__ x,
              const void* __restrict__ wq, const void* __restrict__ wk,
              const void* __restrict__ wv, const void* __restrict__ wo,
              u16* __restrict__ xb, u16* __restrict__ wqkv,
              u16* __restrict__ wob, const int* __restrict__ flag) {
  const int mode = *flag;
  const int bid = blockIdx.x;
  if (bid < 4096) {
    cast8(x, xb, mode, (size_t)bid * 256 + threadIdx.x);
  } else {
    const size_t DD8 = (size_t)1024 * 1024 / 8;
    const int m = (bid - 4096) >> 9;
    const size_t i = ((size_t)((bid - 4096) & 511)) * 256 + threadIdx.x;
    const void* src = (m == 0) ? wq : (m == 1) ? wk : (m == 2) ? wv : wo;
    u16* dst = (m < 3) ? (wqkv + (size_t)m * DD8 * 8) : wob;
    cast8(src, dst, mode, i);
  }
}

// ---------------------------------------------------------------------------
// GEMM  C = A @ W^T + bias.  BM=BN=128, BK=64, 256 thr (2x2 waves).
// Named prefetch regs (no scratch), lgkm-only barriers, XOR-swizzled LDS
// (conflicts = 0, verified R5/R6).
// MODE 0 (QKV): band 0 -> o0 = qb (pre-scaled by SL2E); band 1 -> o1 = kb;
//               band 2 -> o2 = vtb[(b*16+h)*64+d][4096] (transposed V).
// MODE 1 (out): o0 = d_out, f32 if input-mode==1 else bf16.
// ---------------------------------------------------------------------------
template <int MODE>
__global__ __launch_bounds__(256)
void gemm_bt(const bf16* __restrict__ A, const bf16* __restrict__ W,
             const void* __restrict__ b0, const void* __restrict__ b1,
             const void* __restrict__ b2, void* __restrict__ o0,
             void* __restrict__ o1, void* __restrict__ o2,
             const int* __restrict__ flag, int M, int N, int K)
{
  __shared__ bf16 As[128 * 64];
  __shared__ bf16 Bs[128 * 64];

  const int mode = *flag;
  const int tid  = threadIdx.x;
  const int wave = tid >> 6, lane = tid & 63;
  const int quad = lane >> 4, l16 = lane & 15;
  const int wm   = wave >> 1, wn  = wave & 1;
  const int m0   = blockIdx.x * 128, n0 = blockIdx.y * 128;

  const int band = n0 >> 10;
  const void* bias = (band == 0) ? b0 : (band == 1) ? b1 : b2;

  const int srow = lane >> 3;          // 0..7
  const int sg   = lane & 7;           // 16B granule 0..7
  const size_t rgs = (size_t)8 * K;    // 8-row group stride
  const bf16* aSrc = A + (size_t)(m0 + wave * 32 + srow) * K + sg * 8;
  const bf16* wSrc = W + (size_t)(n0 + wave * 32 + srow) * K + sg * 8;
  bf16* aDst = As + (wave * 32 + srow) * 64 + ((sg ^ srow) * 8);
  bf16* wDst = Bs + (wave * 32 + srow) * 64 + ((sg ^ srow) * 8);

  const int niter = K >> 6;

  uint4 a0 = *(const uint4*)(aSrc);
  uint4 a1 = *(const uint4*)(aSrc + rgs);
  uint4 a2 = *(const uint4*)(aSrc + 2 * rgs);
  uint4 a3 = *(const uint4*)(aSrc + 3 * rgs);
  uint4 w0 = *(const uint4*)(wSrc);
  uint4 w1 = *(const uint4*)(wSrc + rgs);
  uint4 w2 = *(const uint4*)(wSrc + 2 * rgs);
  uint4 w3 = *(const uint4*)(wSrc + 3 * rgs);
  aSrc += 64; wSrc += 64;

  f32x4 acc[4][4] = {};

  const int arow[4] = { (wm * 64 + 0 * 16 + l16) * 64, (wm * 64 + 1 * 16 + l16) * 64,
                        (wm * 64 + 2 * 16 + l16) * 64, (wm * 64 + 3 * 16 + l16) * 64 };
  const int brow[4] = { (wn * 64 + 0 * 16 + l16) * 64, (wn * 64 + 1 * 16 + l16) * 64,
                        (wn * 64 + 2 * 16 + l16) * 64, (wn * 64 + 3 * 16 + l16) * 64 };
  const int r7 = l16 & 7;

  for (int t = 0; t < niter; ++t) {
    if (t) barrier_lgkm();
    *(uint4*)(aDst)        = a0;
    *(uint4*)(aDst + 512)  = a1;
    *(uint4*)(aDst + 1024) = a2;
    *(uint4*)(aDst + 1536) = a3;
    *(uint4*)(wDst)        = w0;
    *(uint4*)(wDst + 512)  = w1;
    *(uint4*)(wDst + 1024) = w2;
    *(uint4*)(wDst + 1536) = w3;
    barrier_lgkm();
    if (t + 1 < niter) {
      a0 = *(const uint4*)(aSrc);
      a1 = *(const uint4*)(aSrc + rgs);
      a2 = *(const uint4*)(aSrc + 2 * rgs);
      a3 = *(const uint4*)(aSrc + 3 * rgs);
      w0 = *(const uint4*)(wSrc);
      w1 = *(const uint4*)(wSrc + rgs);
      w2 = *(const uint4*)(wSrc + 2 * rgs);
      w3 = *(const uint4*)(wSrc + 3 * rgs);
      aSrc += 64; wSrc += 64;
    }
#pragma unroll
    for (int kk = 0; kk < 2; ++kk) {
      bf16x8 af[4], bw[4];
#pragma unroll
      for (int mt = 0; mt < 4; ++mt)
        af[mt] = *(const bf16x8*)(As + arow[mt] + (((kk * 4 + quad) ^ r7) * 8));
#pragma unroll
      for (int nt = 0; nt < 4; ++nt)
        bw[nt] = *(const bf16x8*)(Bs + brow[nt] + (((kk * 4 + quad) ^ r7) * 8));
#pragma unroll
      for (int mt = 0; mt < 4; ++mt)
#pragma unroll
        for (int nt = 0; nt < 4; ++nt)
          acc[mt][nt] = MFMA(af[mt], bw[nt], acc[mt][nt]);
    }
  }

#pragma unroll
  for (int nt = 0; nt < 4; ++nt) {
    const int col = n0 + wn * 64 + nt * 16 + l16;
    const int cl  = col & 1023;
    const float bv = mode ? ((const float*)bias)[cl]
                          : bf16_to_f32(((const u16*)bias)[cl]);
#pragma unroll
    for (int mt = 0; mt < 4; ++mt) {
      const int rbase = m0 + wm * 64 + mt * 16 + quad * 4;
      if (MODE == 1) {
#pragma unroll
        for (int r = 0; r < 4; ++r) {
          const float val = acc[mt][nt][r] + bv;
          const size_t idx = (size_t)(rbase + r) * N + col;
          if (mode) ((float*)o0)[idx] = val;
          else      ((u16*)o0)[idx]   = f32_to_bf16_rtne(val);
        }
      } else if (band == 2) {
        const int hh = cl >> 6, dd = cl & 63;
        const int bb = rbase >> 12, tl = rbase & 4095;
        u16* dst = (u16*)o2 + ((size_t)((bb * 16 + hh) * 64 + dd)) * 4096 + tl;
        uint2 pk;
        pk.x = pk2bf(acc[mt][nt][0] + bv, acc[mt][nt][1] + bv);
        pk.y = pk2bf(acc[mt][nt][2] + bv, acc[mt][nt][3] + bv);
        *(uint2*)dst = pk;
      } else {
        u16* dst = (u16*)((band == 0) ? o0 : o1);
        const float sc = (band == 0) ? SL2E : 1.0f;
#pragma unroll
        for (int r = 0; r < 4; ++r)
          dst[(size_t)(rbase + r) * 1024 + cl] =
              f32_to_bf16_rtne((acc[mt][nt][r] + bv) * sc);
      }
    }
  }
}

// ---------------------------------------------------------------------------
// Sliding-window attention, S^T formulation, fixed-max softmax,
// DOUBLE-BUFFERED K/V LDS: one barrier per tile; tile t+1's ds_writes and
// tile t+2's global loads overlap tile t's compute. Loop unrolled x2 so the
// buffer index is compile-time and prefetch regs stay named (no scratch).
// grid = 1024: bid = qt*256 + g, g = (b<<7)|(c<<4)|h, qt 0..3 (128 q/block).
// ---------------------------------------------------------------------------
__global__ __launch_bounds__(256)
void attn_swin(const bf16* __restrict__ qb, const bf16* __restrict__ kb,
               const bf16* __restrict__ vtb, u16* __restrict__ ctx)
{
  __shared__ __align__(16) bf16 Ks[2][64 * 72];
  __shared__ __align__(16) bf16 Vts[2][64 * 72];

  int bid = blockIdx.x;
  const int g  = bid & 255, qt = bid >> 8;
  const int h  = g & 15, c = (g >> 4) & 7, b = g >> 7;

  const int tid  = threadIdx.x;
  const int w    = tid >> 6, lane = tid & 63;
  const int quad = lane >> 4, l16 = lane & 15;

  const int tq0  = c * 512 + qt * 128;
  const int hoff = h * 64;
  const int kstart = (c == 0) ? 0 : (c - 1) * 512;
  const int nkt    = (c == 0) ? 8 : 16;     // always even

  // ---- Q B-frags straight from global ----
  bf16x8 qf[2][2];
#pragma unroll
  for (int u = 0; u < 2; ++u) {
    const bf16* qr = qb + ((size_t)(b * 4096 + tq0 + w * 32 + u * 16 + l16)) * 1024 + hoff;
    qf[u][0] = *(const bf16x8*)(qr + quad * 8);
    qf[u][1] = *(const bf16x8*)(qr + 32 + quad * 8);
  }

  // ---- staging addresses ----
  const int m    = tid >> 2;            // LDS row 0..63
  const int cseg = (tid & 3) * 16;      // 32B column segment
  const int sig  = (((m >> 4) & 1) << 5) | (((m >> 2) & 3) << 3)
                 | (((m >> 5) & 1) << 2) | (m & 3);
  const bf16* kgp = kb + ((size_t)(b * 4096 + kstart + sig)) * 1024 + hoff + cseg;
  const bf16* vgp = vtb + ((size_t)((b * 16 + h) * 64 + m)) * 4096 + kstart + cseg;
  const int soff = m * 72 + cseg;

  float l_i[2] = {0.f, 0.f};
  f32x4 o[2][4] = {};

  // ---- prologue: tile0 -> buf0; prefetch tile1 into named regs ----
  uint4 ka0 = *(const uint4*)(kgp), ka1 = *(const uint4*)(kgp + 8);
  uint4 va0 = *(const uint4*)(vgp), va1 = *(const uint4*)(vgp + 8);
  kgp += (size_t)64 * 1024; vgp += 64;
  *(uint4*)(Ks[0] + soff) = ka0; *(uint4*)(Ks[0] + soff + 8) = ka1;
  *(uint4*)(Vts[0] + soff) = va0; *(uint4*)(Vts[0] + soff + 8) = va1;
  ka0 = *(const uint4*)(kgp); ka1 = *(const uint4*)(kgp + 8);
  va0 = *(const uint4*)(vgp); va1 = *(const uint4*)(vgp + 8);
  kgp += (size_t)64 * 1024; vgp += 64;
  barrier_lgkm();

  typedef union { u32 d[4]; bf16x8 v; } fragu;

  // one tile's compute from buffer `buf` (compile-time constant)
  auto compute = [&](const bf16* ksb, const bf16* vtsb) {
    f32x4 s[2][4] = {};
#pragma unroll
    for (int kt = 0; kt < 4; ++kt) {
      const bf16* kr = ksb + (kt * 16 + l16) * 72;
      bf16x8 kf0 = *(const bf16x8*)(kr + quad * 8);
      bf16x8 kf1 = *(const bf16x8*)(kr + 32 + quad * 8);
      s[0][kt] = MFMA(kf0, qf[0][0], s[0][kt]);
      s[0][kt] = MFMA(kf1, qf[0][1], s[0][kt]);
      s[1][kt] = MFMA(kf0, qf[1][0], s[1][kt]);
      s[1][kt] = MFMA(kf1, qf[1][1], s[1][kt]);
    }
    fragu pf[2][2];
#pragma unroll
    for (int u = 0; u < 2; ++u) {
      float rs = 0.f;
#pragma unroll
      for (int kt = 0; kt < 4; ++kt)
#pragma unroll
        for (int r = 0; r < 4; ++r) {
          const float p = __builtin_amdgcn_exp2f(s[u][kt][r]);
          s[u][kt][r] = p;
          rs += p;
        }
      rs += __shfl_xor(rs, 16);
      rs += __shfl_xor(rs, 32);
      l_i[u] += rs;
#pragma unroll
      for (int hh = 0; hh < 2; ++hh)
#pragma unroll
        for (int dw = 0; dw < 4; ++dw) {
          const int kt = 2 * (dw >> 1) + hh, r0 = 2 * (dw & 1);
          pf[u][hh].d[dw] = pk2bf_rtz(s[u][kt][r0], s[u][kt][r0 + 1]);
        }
    }
#pragma unroll
    for (int dt = 0; dt < 4; ++dt) {
      const bf16* vr = vtsb + (dt * 16 + l16) * 72;
      bf16x8 vf0 = *(const bf16x8*)(vr + quad * 8);
      bf16x8 vf1 = *(const bf16x8*)(vr + 32 + quad * 8);
      o[0][dt] = MFMA(vf0, pf[0][0].v, o[0][dt]);
      o[0][dt] = MFMA(vf1, pf[0][1].v, o[0][dt]);
      o[1][dt] = MFMA(vf0, pf[1][0].v, o[1][dt]);
      o[1][dt] = MFMA(vf1, pf[1][1].v, o[1][dt]);
    }
  };

  for (int t = 0; t < nkt; t += 2) {
    // ---- even iter t: compute buf0; write tile t+1 -> buf1; load t+2 ----
    *(uint4*)(Ks[1] + soff) = ka0; *(uint4*)(Ks[1] + soff + 8) = ka1;
    *(uint4*)(Vts[1] + soff) = va0; *(uint4*)(Vts[1] + soff + 8) = va1;
    if (t + 2 < nkt) {
      ka0 = *(const uint4*)(kgp); ka1 = *(const uint4*)(kgp + 8);
      va0 = *(const uint4*)(vgp); va1 = *(const uint4*)(vgp + 8);
      kgp += (size_t)64 * 1024; vgp += 64;
    }
    compute(Ks[0], Vts[0]);
    barrier_lgkm();

    // ---- odd iter t+1: compute buf1; write tile t+2 -> buf0; load t+3 ----
    if (t + 2 < nkt) {
      *(uint4*)(Ks[0] + soff) = ka0; *(uint4*)(Ks[0] + soff + 8) = ka1;
      *(uint4*)(Vts[0] + soff) = va0; *(uint4*)(Vts[0] + soff + 8) = va1;
      if (t + 3 < nkt) {
        ka0 = *(const uint4*)(kgp); ka1 = *(const uint4*)(kgp + 8);
        va0 = *(const uint4*)(vgp); va1 = *(const uint4*)(vgp + 8);
        kgp += (size_t)64 * 1024; vgp += 64;
      }
    }
    compute(Ks[1], Vts[1]);
    barrier_lgkm();
  }

  // ---- epilogue: O^T element (d = dt*16+quad*4+r, q = l16) ----
#pragma unroll
  for (int u = 0; u < 2; ++u) {
    const float inv = 1.0f / l_i[u];
    const int qrow = tq0 + w * 32 + u * 16 + l16;
    u16* crow = ctx + ((size_t)(b * 4096 + qrow)) * 1024 + hoff;
#pragma unroll
    for (int dt = 0; dt < 4; ++dt) {
      uint2 pk;
      pk.x = pk2bf(o[u][dt][0] * inv, o[u][dt][1] * inv);
      pk.y = pk2bf(o[u][dt][2] * inv, o[u][dt][3] * inv);
      *(uint2*)(crow + dt * 16 + quad * 4) = pk;
    }
  }
}

// ---------------------------------------------------------------------------
extern "C" void kernel_launch(void* const* d_in, const int* in_sizes, int n_in,
                              void* d_out, int out_size, void* d_ws, size_t ws_size,
                              hipStream_t stream) {
  const void* x  = d_in[0];
  const void* Wq = d_in[1];
  const void* bq = d_in[2];
  const void* Wk = d_in[3];
  const void* bk = d_in[4];
  const void* Wv = d_in[5];
  const void* bv = d_in[6];
  const void* Wo = d_in[7];
  const void* bo = d_in[8];

  const size_t MD = (size_t)8192 * 1024;   // [B*L, D] elements
  const size_t DD = (size_t)1024 * 1024;   // [D, D] elements

  char* ws = (char*)d_ws;
  int*  flag  = (int*)ws;                     ws += 256;
  u16*  xb    = (u16*)ws;                     ws += MD * 2;
  u16*  Wqkvb = (u16*)ws;                     ws += 3 * DD * 2;
  u16*  Wob   = (u16*)ws;                     ws += DD * 2;
  u16*  qbuf  = (u16*)ws;                     ws += MD * 2;
  u16*  kbuf  = (u16*)ws;                     ws += MD * 2;
  u16*  vtb   = (u16*)ws;                     ws += MD * 2;
  u16*  ctx   = (u16*)ws;                     // + MD*2  (~88 MB total)

  detect_mode<<<dim3(1), dim3(256), 0, stream>>>((const u16*)x, flag);
  cast_all<<<dim3(6144), dim3(256), 0, stream>>>(x, Wq, Wk, Wv, Wo,
                                                 xb, Wqkvb, Wob, flag);

  // fused QKV projection with splitting epilogue (q scaled, v transposed)
  gemm_bt<0><<<dim3(64, 24), dim3(256), 0, stream>>>(
      (const bf16*)xb, (const bf16*)Wqkvb, bq, bk, bv,
      qbuf, kbuf, vtb, flag, 8192, 3072, 1024);

  attn_swin<<<dim3(1024), dim3(256), 0, stream>>>(
      (const bf16*)qbuf, (const bf16*)kbuf, (const bf16*)vtb, ctx);

  gemm_bt<1><<<dim3(64, 8), dim3(256), 0, stream>>>(
      (const bf16*)ctx, (const bf16*)Wob, bo, bo, bo,
      d_out, nullptr, nullptr, flag, 8192, 1024, 1024);
}

// Round 8
// 235.845 us; speedup vs baseline: 2.1177x; 1.0115x over previous
//
#include <hip/hip_runtime.h>
#include <hip/hip_bf16.h>

typedef __hip_bfloat16 bf16;
typedef __attribute__((ext_vector_type(8))) short bf16x8;   // 8 bf16 = 4 VGPRs (MFMA A/B frag)
typedef __attribute__((ext_vector_type(4))) float f32x4;    // MFMA C/D frag
typedef unsigned int u32;
typedef unsigned short u16;

#define MFMA(a,b,c) __builtin_amdgcn_mfma_f32_16x16x32_bf16((a),(b),(c),0,0,0)

__device__ __forceinline__ u16 f32_to_bf16_rtne(float f) {
  u32 b = __builtin_bit_cast(u32, f);
  b += 0x7FFFu + ((b >> 16) & 1u);
  return (u16)(b >> 16);
}
// pack two f32 -> bf16 pair, RTNE
__device__ __forceinline__ u32 pk2bf(float a, float b) {
  u32 ua = __builtin_bit_cast(u32, a); ua += 0x7FFFu + ((ua >> 16) & 1u);
  u32 ub = __builtin_bit_cast(u32, b); ub += 0x7FFFu + ((ub >> 16) & 1u);
  return __builtin_amdgcn_perm(ub, ua, 0x07060302u);
}
// pack two f32 -> bf16 pair, RTZ (P-matrix hot path: 1 v_perm)
__device__ __forceinline__ u32 pk2bf_rtz(float a, float b) {
  return __builtin_amdgcn_perm(__builtin_bit_cast(u32, b),
                               __builtin_bit_cast(u32, a), 0x07060302u);
}
// 8 f32 (two uint4) -> 8 bf16 (one uint4), RTNE
__device__ __forceinline__ uint4 cvt8(uint4 lo, uint4 hi) {
  const float4 fl = __builtin_bit_cast(float4, lo);
  const float4 fh = __builtin_bit_cast(float4, hi);
  uint4 r;
  r.x = pk2bf(fl.x, fl.y); r.y = pk2bf(fl.z, fl.w);
  r.z = pk2bf(fh.x, fh.y); r.w = pk2bf(fh.z, fh.w);
  return r;
}

// lgkm-only barrier: LDS ops drained, but outstanding global->reg prefetch
// loads stay IN FLIGHT across the barrier (no vmcnt(0) drain).
__device__ __forceinline__ void barrier_lgkm() {
  asm volatile("s_waitcnt lgkmcnt(0)\n\ts_barrier" ::: "memory");
}

static constexpr float SL2E = 0.125f * 1.44269504f;  // 1/sqrt(dh) * log2(e)

// ---------------------------------------------------------------------------
// Weight cast f32 -> bf16 (x is cast inside the QKV GEMM's staging path).
// grid 2048: blocks [512m, 512m+512) handle Wq/Wk/Wv -> wqkv, Wo -> wob.
// ---------------------------------------------------------------------------
__global__ __launch_bounds__(256)
void cast_w(const float* __restrict__ wq, const float* __restrict__ wk,
            const float* __restrict__ wv, const float* __restrict__ wo,
            u16* __restrict__ wqkv, u16* __restrict__ wob) {
  const size_t DD8 = (size_t)1024 * 1024 / 8;
  const int m = blockIdx.x >> 9;
  const size_t i = ((size_t)(blockIdx.x & 511)) * 256 + threadIdx.x;
  const float* src = (m == 0) ? wq : (m == 1) ? wk : (m == 2) ? wv : wo;
  u16* dst = (m < 3) ? (wqkv + (size_t)m * DD8 * 8) : wob;
  const float4* s = (const float4*)src + i * 2;
  uint4 v = cvt8(__builtin_bit_cast(uint4, s[0]), __builtin_bit_cast(uint4, s[1]));
  ((uint4*)dst)[i] = v;
}

// ---------------------------------------------------------------------------
// GEMM  C = A @ W^T + bias.  BM=BN=128, BK=64, 256 thr (2x2 waves).
// Named prefetch regs (no scratch), lgkm-only barriers, XOR-swizzled LDS
// (conflicts = 0, verified R5-R7).
// CASTA=1: A is f32 (x), converted to bf16 in-register during staging.
// CASTA=0: A is bf16 (ctx).
// MODE 0 (QKV): band 0 -> o0 = qb (pre-scaled by SL2E); band 1 -> o1 = kb;
//               band 2 -> o2 = vtb[(b*16+h)*64+d][4096] (transposed V).
// MODE 1 (out): o0 = d_out, f32.
// ---------------------------------------------------------------------------
template <int MODE, int CASTA>
__global__ __launch_bounds__(256)
void gemm_bt(const void* __restrict__ Asrc, const bf16* __restrict__ W,
             const float* __restrict__ b0, const float* __restrict__ b1,
             const float* __restrict__ b2, void* __restrict__ o0,
             void* __restrict__ o1, void* __restrict__ o2,
             int M, int N, int K)
{
  __shared__ bf16 As[128 * 64];
  __shared__ bf16 Bs[128 * 64];

  const int tid  = threadIdx.x;
  const int wave = tid >> 6, lane = tid & 63;
  const int quad = lane >> 4, l16 = lane & 15;
  const int wm   = wave >> 1, wn  = wave & 1;
  const int m0   = blockIdx.x * 128, n0 = blockIdx.y * 128;

  const int band = n0 >> 10;
  const float* bias = (band == 0) ? b0 : (band == 1) ? b1 : b2;

  const int srow = lane >> 3;          // 0..7
  const int sg   = lane & 7;           // 16B-dest granule 0..7
  const size_t rgs = (size_t)8 * K;    // 8-row group stride (elements)
  const bf16*  aSrcH = (const bf16*)Asrc  + (size_t)(m0 + wave * 32 + srow) * K + sg * 8;
  const float* aSrcF = (const float*)Asrc + (size_t)(m0 + wave * 32 + srow) * K + sg * 8;
  const bf16*  wSrc  = W + (size_t)(n0 + wave * 32 + srow) * K + sg * 8;
  bf16* aDst = As + (wave * 32 + srow) * 64 + ((sg ^ srow) * 8);
  bf16* wDst = Bs + (wave * 32 + srow) * 64 + ((sg ^ srow) * 8);

  const int niter = K >> 6;

  // prefetch tile 0 (NAMED registers only -> no scratch; lesson of R5)
  uint4 a0, a1, a2, a3;        // bf16 path
  uint4 a0h, a1h, a2h, a3h;    // f32 path second halves
  if (CASTA) {
    a0 = *(const uint4*)(aSrcF);            a0h = *(const uint4*)(aSrcF + 4);
    a1 = *(const uint4*)(aSrcF + rgs);      a1h = *(const uint4*)(aSrcF + rgs + 4);
    a2 = *(const uint4*)(aSrcF + 2 * rgs);  a2h = *(const uint4*)(aSrcF + 2 * rgs + 4);
    a3 = *(const uint4*)(aSrcF + 3 * rgs);  a3h = *(const uint4*)(aSrcF + 3 * rgs + 4);
    aSrcF += 64;
  } else {
    a0 = *(const uint4*)(aSrcH);
    a1 = *(const uint4*)(aSrcH + rgs);
    a2 = *(const uint4*)(aSrcH + 2 * rgs);
    a3 = *(const uint4*)(aSrcH + 3 * rgs);
    aSrcH += 64;
  }
  uint4 w0 = *(const uint4*)(wSrc);
  uint4 w1 = *(const uint4*)(wSrc + rgs);
  uint4 w2 = *(const uint4*)(wSrc + 2 * rgs);
  uint4 w3 = *(const uint4*)(wSrc + 3 * rgs);
  wSrc += 64;

  f32x4 acc[4][4] = {};

  const int arow[4] = { (wm * 64 + 0 * 16 + l16) * 64, (wm * 64 + 1 * 16 + l16) * 64,
                        (wm * 64 + 2 * 16 + l16) * 64, (wm * 64 + 3 * 16 + l16) * 64 };
  const int brow[4] = { (wn * 64 + 0 * 16 + l16) * 64, (wn * 64 + 1 * 16 + l16) * 64,
                        (wn * 64 + 2 * 16 + l16) * 64, (wn * 64 + 3 * 16 + l16) * 64 };
  const int r7 = l16 & 7;

  for (int t = 0; t < niter; ++t) {
    if (t) barrier_lgkm();
    if (CASTA) {
      *(uint4*)(aDst)        = cvt8(a0, a0h);
      *(uint4*)(aDst + 512)  = cvt8(a1, a1h);
      *(uint4*)(aDst + 1024) = cvt8(a2, a2h);
      *(uint4*)(aDst + 1536) = cvt8(a3, a3h);
    } else {
      *(uint4*)(aDst)        = a0;
      *(uint4*)(aDst + 512)  = a1;
      *(uint4*)(aDst + 1024) = a2;
      *(uint4*)(aDst + 1536) = a3;
    }
    *(uint4*)(wDst)        = w0;
    *(uint4*)(wDst + 512)  = w1;
    *(uint4*)(wDst + 1024) = w2;
    *(uint4*)(wDst + 1536) = w3;
    barrier_lgkm();                        // writes visible; vmem NOT drained
    if (t + 1 < niter) {                   // re-fill the same named regs
      if (CASTA) {
        a0 = *(const uint4*)(aSrcF);            a0h = *(const uint4*)(aSrcF + 4);
        a1 = *(const uint4*)(aSrcF + rgs);      a1h = *(const uint4*)(aSrcF + rgs + 4);
        a2 = *(const uint4*)(aSrcF + 2 * rgs);  a2h = *(const uint4*)(aSrcF + 2 * rgs + 4);
        a3 = *(const uint4*)(aSrcF + 3 * rgs);  a3h = *(const uint4*)(aSrcF + 3 * rgs + 4);
        aSrcF += 64;
      } else {
        a0 = *(const uint4*)(aSrcH);
        a1 = *(const uint4*)(aSrcH + rgs);
        a2 = *(const uint4*)(aSrcH + 2 * rgs);
        a3 = *(const uint4*)(aSrcH + 3 * rgs);
        aSrcH += 64;
      }
      w0 = *(const uint4*)(wSrc);
      w1 = *(const uint4*)(wSrc + rgs);
      w2 = *(const uint4*)(wSrc + 2 * rgs);
      w3 = *(const uint4*)(wSrc + 3 * rgs);
      wSrc += 64;
    }
#pragma unroll
    for (int kk = 0; kk < 2; ++kk) {
      bf16x8 af[4], bw[4];
#pragma unroll
      for (int mt = 0; mt < 4; ++mt)
        af[mt] = *(const bf16x8*)(As + arow[mt] + (((kk * 4 + quad) ^ r7) * 8));
#pragma unroll
      for (int nt = 0; nt < 4; ++nt)
        bw[nt] = *(const bf16x8*)(Bs + brow[nt] + (((kk * 4 + quad) ^ r7) * 8));
#pragma unroll
      for (int mt = 0; mt < 4; ++mt)
#pragma unroll
        for (int nt = 0; nt < 4; ++nt)
          acc[mt][nt] = MFMA(af[mt], bw[nt], acc[mt][nt]);
    }
  }

  // epilogue: C/D layout col = lane&15, row = quad*4 + reg
#pragma unroll
  for (int nt = 0; nt < 4; ++nt) {
    const int col = n0 + wn * 64 + nt * 16 + l16;
    const int cl  = col & 1023;
    const float bv = bias[cl];
#pragma unroll
    for (int mt = 0; mt < 4; ++mt) {
      const int rbase = m0 + wm * 64 + mt * 16 + quad * 4;
      if (MODE == 1) {
#pragma unroll
        for (int r = 0; r < 4; ++r)
          ((float*)o0)[(size_t)(rbase + r) * N + col] = acc[mt][nt][r] + bv;
      } else if (band == 2) {
        // transposed V: vt[(b*16+h)*64 + d][token], 4 consecutive tokens packed
        const int hh = cl >> 6, dd = cl & 63;
        const int bb = rbase >> 12, tl = rbase & 4095;
        u16* dst = (u16*)o2 + ((size_t)((bb * 16 + hh) * 64 + dd)) * 4096 + tl;
        uint2 pk;
        pk.x = pk2bf(acc[mt][nt][0] + bv, acc[mt][nt][1] + bv);
        pk.y = pk2bf(acc[mt][nt][2] + bv, acc[mt][nt][3] + bv);
        *(uint2*)dst = pk;
      } else {
        u16* dst = (u16*)((band == 0) ? o0 : o1);
        const float sc = (band == 0) ? SL2E : 1.0f;
#pragma unroll
        for (int r = 0; r < 4; ++r)
          dst[(size_t)(rbase + r) * 1024 + cl] =
              f32_to_bf16_rtne((acc[mt][nt][r] + bv) * sc);
      }
    }
  }
}

// ---------------------------------------------------------------------------
// Sliding-window attention, S^T formulation, fixed-max softmax,
// double-buffered K/V LDS, one lgkm barrier per tile (verified R7).
// grid = 1024: bid = qt*256 + g, g = (b<<7)|(c<<4)|h, qt 0..3 (128 q/block).
// ---------------------------------------------------------------------------
__global__ __launch_bounds__(256)
void attn_swin(const bf16* __restrict__ qb, const bf16* __restrict__ kb,
               const bf16* __restrict__ vtb, u16* __restrict__ ctx)
{
  __shared__ __align__(16) bf16 Ks[2][64 * 72];
  __shared__ __align__(16) bf16 Vts[2][64 * 72];

  int bid = blockIdx.x;
  const int g  = bid & 255, qt = bid >> 8;
  const int h  = g & 15, c = (g >> 4) & 7, b = g >> 7;

  const int tid  = threadIdx.x;
  const int w    = tid >> 6, lane = tid & 63;
  const int quad = lane >> 4, l16 = lane & 15;

  const int tq0  = c * 512 + qt * 128;
  const int hoff = h * 64;
  const int kstart = (c == 0) ? 0 : (c - 1) * 512;
  const int nkt    = (c == 0) ? 8 : 16;     // always even

  // ---- Q B-frags straight from global ----
  bf16x8 qf[2][2];
#pragma unroll
  for (int u = 0; u < 2; ++u) {
    const bf16* qr = qb + ((size_t)(b * 4096 + tq0 + w * 32 + u * 16 + l16)) * 1024 + hoff;
    qf[u][0] = *(const bf16x8*)(qr + quad * 8);
    qf[u][1] = *(const bf16x8*)(qr + 32 + quad * 8);
  }

  // ---- staging addresses ----
  const int m    = tid >> 2;            // LDS row 0..63
  const int cseg = (tid & 3) * 16;      // 32B column segment
  const int sig  = (((m >> 4) & 1) << 5) | (((m >> 2) & 3) << 3)
                 | (((m >> 5) & 1) << 2) | (m & 3);
  const bf16* kgp = kb + ((size_t)(b * 4096 + kstart + sig)) * 1024 + hoff + cseg;
  const bf16* vgp = vtb + ((size_t)((b * 16 + h) * 64 + m)) * 4096 + kstart + cseg;
  const int soff = m * 72 + cseg;

  float l_i[2] = {0.f, 0.f};
  f32x4 o[2][4] = {};

  // ---- prologue: tile0 -> buf0; prefetch tile1 into named regs ----
  uint4 ka0 = *(const uint4*)(kgp), ka1 = *(const uint4*)(kgp + 8);
  uint4 va0 = *(const uint4*)(vgp), va1 = *(const uint4*)(vgp + 8);
  kgp += (size_t)64 * 1024; vgp += 64;
  *(uint4*)(Ks[0] + soff) = ka0; *(uint4*)(Ks[0] + soff + 8) = ka1;
  *(uint4*)(Vts[0] + soff) = va0; *(uint4*)(Vts[0] + soff + 8) = va1;
  ka0 = *(const uint4*)(kgp); ka1 = *(const uint4*)(kgp + 8);
  va0 = *(const uint4*)(vgp); va1 = *(const uint4*)(vgp + 8);
  kgp += (size_t)64 * 1024; vgp += 64;
  barrier_lgkm();

  typedef union { u32 d[4]; bf16x8 v; } fragu;

  auto compute = [&](const bf16* ksb, const bf16* vtsb) {
    f32x4 s[2][4] = {};
#pragma unroll
    for (int kt = 0; kt < 4; ++kt) {
      const bf16* kr = ksb + (kt * 16 + l16) * 72;
      bf16x8 kf0 = *(const bf16x8*)(kr + quad * 8);
      bf16x8 kf1 = *(const bf16x8*)(kr + 32 + quad * 8);
      s[0][kt] = MFMA(kf0, qf[0][0], s[0][kt]);
      s[0][kt] = MFMA(kf1, qf[0][1], s[0][kt]);
      s[1][kt] = MFMA(kf0, qf[1][0], s[1][kt]);
      s[1][kt] = MFMA(kf1, qf[1][1], s[1][kt]);
    }
    fragu pf[2][2];
#pragma unroll
    for (int u = 0; u < 2; ++u) {
      float rs = 0.f;
#pragma unroll
      for (int kt = 0; kt < 4; ++kt)
#pragma unroll
        for (int r = 0; r < 4; ++r) {
          const float p = __builtin_amdgcn_exp2f(s[u][kt][r]);
          s[u][kt][r] = p;
          rs += p;
        }
      rs += __shfl_xor(rs, 16);
      rs += __shfl_xor(rs, 32);
      l_i[u] += rs;
#pragma unroll
      for (int hh = 0; hh < 2; ++hh)
#pragma unroll
        for (int dw = 0; dw < 4; ++dw) {
          const int kt = 2 * (dw >> 1) + hh, r0 = 2 * (dw & 1);
          pf[u][hh].d[dw] = pk2bf_rtz(s[u][kt][r0], s[u][kt][r0 + 1]);
        }
    }
#pragma unroll
    for (int dt = 0; dt < 4; ++dt) {
      const bf16* vr = vtsb + (dt * 16 + l16) * 72;
      bf16x8 vf0 = *(const bf16x8*)(vr + quad * 8);
      bf16x8 vf1 = *(const bf16x8*)(vr + 32 + quad * 8);
      o[0][dt] = MFMA(vf0, pf[0][0].v, o[0][dt]);
      o[0][dt] = MFMA(vf1, pf[0][1].v, o[0][dt]);
      o[1][dt] = MFMA(vf0, pf[1][0].v, o[1][dt]);
      o[1][dt] = MFMA(vf1, pf[1][1].v, o[1][dt]);
    }
  };

  for (int t = 0; t < nkt; t += 2) {
    // even iter t: compute buf0; write tile t+1 -> buf1; load t+2
    *(uint4*)(Ks[1] + soff) = ka0; *(uint4*)(Ks[1] + soff + 8) = ka1;
    *(uint4*)(Vts[1] + soff) = va0; *(uint4*)(Vts[1] + soff + 8) = va1;
    if (t + 2 < nkt) {
      ka0 = *(const uint4*)(kgp); ka1 = *(const uint4*)(kgp + 8);
      va0 = *(const uint4*)(vgp); va1 = *(const uint4*)(vgp + 8);
      kgp += (size_t)64 * 1024; vgp += 64;
    }
    compute(Ks[0], Vts[0]);
    barrier_lgkm();

    // odd iter t+1: compute buf1; write tile t+2 -> buf0; load t+3
    if (t + 2 < nkt) {
      *(uint4*)(Ks[0] + soff) = ka0; *(uint4*)(Ks[0] + soff + 8) = ka1;
      *(uint4*)(Vts[0] + soff) = va0; *(uint4*)(Vts[0] + soff + 8) = va1;
      if (t + 3 < nkt) {
        ka0 = *(const uint4*)(kgp); ka1 = *(const uint4*)(kgp + 8);
        va0 = *(const uint4*)(vgp); va1 = *(const uint4*)(vgp + 8);
        kgp += (size_t)64 * 1024; vgp += 64;
      }
    }
    compute(Ks[1], Vts[1]);
    barrier_lgkm();
  }

  // ---- epilogue: O^T element (d = dt*16+quad*4+r, q = l16) ----
#pragma unroll
  for (int u = 0; u < 2; ++u) {
    const float inv = 1.0f / l_i[u];
    const int qrow = tq0 + w * 32 + u * 16 + l16;
    u16* crow = ctx + ((size_t)(b * 4096 + qrow)) * 1024 + hoff;
#pragma unroll
    for (int dt = 0; dt < 4; ++dt) {
      uint2 pk;
      pk.x = pk2bf(o[u][dt][0] * inv, o[u][dt][1] * inv);
      pk.y = pk2bf(o[u][dt][2] * inv, o[u][dt][3] * inv);
      *(uint2*)(crow + dt * 16 + quad * 4) = pk;
    }
  }
}

// ---------------------------------------------------------------------------
extern "C" void kernel_launch(void* const* d_in, const int* in_sizes, int n_in,
                              void* d_out, int out_size, void* d_ws, size_t ws_size,
                              hipStream_t stream) {
  const float* x  = (const float*)d_in[0];
  const float* Wq = (const float*)d_in[1];
  const float* bq = (const float*)d_in[2];
  const float* Wk = (const float*)d_in[3];
  const float* bk = (const float*)d_in[4];
  const float* Wv = (const float*)d_in[5];
  const float* bv = (const float*)d_in[6];
  const float* Wo = (const float*)d_in[7];
  const float* bo = (const float*)d_in[8];

  const size_t MD = (size_t)8192 * 1024;   // [B*L, D] elements
  const size_t DD = (size_t)1024 * 1024;   // [D, D] elements

  char* ws = (char*)d_ws;
  u16*  Wqkvb = (u16*)ws;                     ws += 3 * DD * 2;
  u16*  Wob   = (u16*)ws;                     ws += DD * 2;
  u16*  qbuf  = (u16*)ws;                     ws += MD * 2;
  u16*  kbuf  = (u16*)ws;                     ws += MD * 2;
  u16*  vtb   = (u16*)ws;                     ws += MD * 2;
  u16*  ctx   = (u16*)ws;                     // + MD*2  (~72 MB total)

  cast_w<<<dim3(2048), dim3(256), 0, stream>>>(Wq, Wk, Wv, Wo, Wqkvb, Wob);

  // fused QKV projection; A = x (f32) cast to bf16 inside the staging path
  gemm_bt<0, 1><<<dim3(64, 24), dim3(256), 0, stream>>>(
      x, (const bf16*)Wqkvb, bq, bk, bv, qbuf, kbuf, vtb, 8192, 3072, 1024);

  attn_swin<<<dim3(1024), dim3(256), 0, stream>>>(
      (const bf16*)qbuf, (const bf16*)kbuf, (const bf16*)vtb, ctx);

  gemm_bt<1, 0><<<dim3(64, 8), dim3(256), 0, stream>>>(
      ctx, (const bf16*)Wob, bo, bo, bo, d_out, nullptr, nullptr, 8192, 1024, 1024);
}